// Round 1
// baseline (31.443 us; speedup 1.0000x reference)
//
#include <hip/hip_runtime.h>

// Problem: B=131072, S=4, D=128, H=1
//   u[b] = dot(x[b,0,:], w) + bias          (reads only first S-slice: 64 MB)
//   y[b] = u[b] + wh * y[b-1]  (scan over b), outputs: h_n (B), y_h (1), y_h (1)
// Strategy: memory-bound dot kernel + exact blocked linear-recurrence scan.

#define B_ROWS 131072
#define CHUNK  256
#define NCHUNK 512   // B_ROWS / CHUNK

// ---- K1: per-row dot product. Half-wave (32 lanes) per row, float4 loads. ----
__global__ __launch_bounds__(256) void k_dot(const float* __restrict__ x,
                                             const float* __restrict__ w,
                                             const float* __restrict__ bias,
                                             float* __restrict__ u) {
    const int gtid = blockIdx.x * 256 + threadIdx.x;
    const int wave = gtid >> 6;
    const int lane = threadIdx.x & 63;
    const int half = lane >> 5;        // which row of the pair
    const int hl   = lane & 31;        // lane within half-wave
    const float4 wv = *reinterpret_cast<const float4*>(w + hl * 4);
    const float  bs = bias[0];
    const int row0 = wave * 16;        // 16 rows per wave (8 iters x 2 rows)
#pragma unroll
    for (int r = 0; r < 8; ++r) {
        const int row = row0 + r * 2 + half;
        const float4 xv = *reinterpret_cast<const float4*>(x + (size_t)row * 512 + hl * 4);
        float s = fmaf(xv.x, wv.x, fmaf(xv.y, wv.y, fmaf(xv.z, wv.z, xv.w * wv.w)));
#pragma unroll
        for (int off = 16; off; off >>= 1) s += __shfl_xor(s, off, 64);
        if (hl == 0) u[row] = s + bs;
    }
}

// ---- K2a: per-chunk local recurrence, emit chunk-final value. ----
__global__ __launch_bounds__(64) void k_chunk_last(const float* __restrict__ u,
                                                   const float* __restrict__ wh_p,
                                                   float* __restrict__ carry) {
    const int k = blockIdx.x * 64 + threadIdx.x;   // chunk id 0..NCHUNK-1
    const float a = wh_p[0];
    const float* up = u + (size_t)k * CHUNK;
    float y = 0.0f;
#pragma unroll 4
    for (int i = 0; i < CHUNK; i += 4) {
        const float4 uv = *reinterpret_cast<const float4*>(up + i);
        y = fmaf(y, a, uv.x);
        y = fmaf(y, a, uv.y);
        y = fmaf(y, a, uv.z);
        y = fmaf(y, a, uv.w);
    }
    carry[k] = y;
}

// ---- K2b: scan NCHUNK carries with coefficient A = wh^CHUNK; write EXCLUSIVE carries. ----
__global__ __launch_bounds__(NCHUNK) void k_scan(const float* __restrict__ carry,
                                                 const float* __restrict__ wh_p,
                                                 float* __restrict__ ex_carry) {
    const int tid  = threadIdx.x;
    const int lane = tid & 63;
    const int wv   = tid >> 6;          // 8 waves
    float A = wh_p[0];
#pragma unroll
    for (int i = 0; i < 8; ++i) A *= A;         // wh^256 == wh^CHUNK
    float c = carry[tid];
    // Hillis-Steele inclusive scan within wave: C_l = v_l + A*C_{l-1}
    float f = A;                                 // A^s at step s
#pragma unroll
    for (int s = 1; s < 64; s <<= 1) {
        float prev = __shfl_up(c, (unsigned)s, 64);
        if (lane >= s) c = fmaf(prev, f, c);
        f *= f;
    }
    // f == A^64 now
    __shared__ float wl[8], wp[8];
    if (lane == 63) wl[wv] = c;
    __syncthreads();
    if (tid == 0) {
        const float A64 = f;
        float p = 0.0f;
#pragma unroll
        for (int w2 = 0; w2 < 8; ++w2) { p = fmaf(p, A64, wl[w2]); wp[w2] = p; }
    }
    __syncthreads();
    float cg = c;
    if (wv > 0) {
        // A^(lane+1) by binary powering (lane+1 in [1,64])
        int e = lane + 1;
        float base = A, acc = 1.0f;
#pragma unroll
        for (int b = 0; b < 7; ++b) { if (e & (1 << b)) acc *= base; base *= base; }
        cg = fmaf(wp[wv - 1], acc, cg);          // global inclusive
    }
    if (tid + 1 < NCHUNK) ex_carry[tid + 1] = cg;
    if (tid == 0) ex_carry[0] = 0.0f;
}

// ---- K3: re-run chunk recurrence seeded with exclusive carry; write h_n (+ y_h tail). ----
__global__ __launch_bounds__(64) void k_apply(const float* __restrict__ u,
                                              const float* __restrict__ wh_p,
                                              const float* __restrict__ ex_carry,
                                              float* __restrict__ out) {
    const int k = blockIdx.x * 64 + threadIdx.x;
    const float a = wh_p[0];
    float y = ex_carry[k];
    const float* up = u + (size_t)k * CHUNK;
    float* op = out + (size_t)k * CHUNK;
#pragma unroll 4
    for (int i = 0; i < CHUNK; i += 4) {
        const float4 uv = *reinterpret_cast<const float4*>(up + i);
        float4 ov;
        y = fmaf(y, a, uv.x); ov.x = y;
        y = fmaf(y, a, uv.y); ov.y = y;
        y = fmaf(y, a, uv.z); ov.z = y;
        y = fmaf(y, a, uv.w); ov.w = y;
        *reinterpret_cast<float4*>(op + i) = ov;
    }
    if (k == NCHUNK - 1) {      // y_h = y_last, duplicated (outputs 1 and 2)
        out[B_ROWS]     = y;
        out[B_ROWS + 1] = y;
    }
}

extern "C" void kernel_launch(void* const* d_in, const int* in_sizes, int n_in,
                              void* d_out, int out_size, void* d_ws, size_t ws_size,
                              hipStream_t stream) {
    const float* x    = (const float*)d_in[0];   // (131072, 4, 128) f32
    const float* w    = (const float*)d_in[1];   // (128, 1) f32
    const float* wh   = (const float*)d_in[2];   // (1, 1) f32
    const float* bias = (const float*)d_in[3];   // (1,) f32
    float* out = (float*)d_out;                  // 131074 f32

    float* u        = (float*)d_ws;              // B_ROWS floats
    float* carry    = u + B_ROWS;                // NCHUNK floats
    float* ex_carry = carry + NCHUNK;            // NCHUNK floats

    // 131072 rows / 16 rows-per-wave = 8192 waves = 2048 blocks of 256
    k_dot<<<2048, 256, 0, stream>>>(x, w, bias, u);
    k_chunk_last<<<NCHUNK / 64, 64, 0, stream>>>(u, wh, carry);
    k_scan<<<1, NCHUNK, 0, stream>>>(carry, wh, ex_carry);
    k_apply<<<NCHUNK / 64, 64, 0, stream>>>(u, wh, ex_carry, out);
}

// Round 2
// 24.075 us; speedup vs baseline: 1.3060x; 1.3060x over previous
//
#include <hip/hip_runtime.h>

// B=131072, S=4, D=128, H=1
//   u[b] = dot(x[b,0,:], w) + bias     (reads only first S-slice: 64 MB)
//   y[b] = u[b] + a*y[b-1],  a = weight_h[0,0] in (0,1)
// 3 kernels: fused dot+local-scan (HBM-bound), tiny carry scan, elementwise apply.

#define B_ROWS 131072
#define CHUNK  256
#define NCHUNK 512   // B_ROWS / CHUNK

template <int CTRL>
__device__ __forceinline__ float dpp_add(float s) {
    int v = __builtin_amdgcn_update_dpp(0, __builtin_bit_cast(int, s), CTRL, 0xF, 0xF, true);
    return s + __builtin_bit_cast(float, v);
}

// ---- K1: block k = chunk k. Dot for 256 rows + weighted inclusive scan. ----
__global__ __launch_bounds__(256) void k_dot_scan(const float* __restrict__ x,
                                                  const float* __restrict__ w,
                                                  const float* __restrict__ wh_p,
                                                  const float* __restrict__ bias,
                                                  float* __restrict__ p,
                                                  float* __restrict__ carry) {
    __shared__ float u_s[CHUNK];
    __shared__ float wl[4];
    const int tid  = threadIdx.x;
    const int wv   = tid >> 6;          // wave 0..3
    const int lane = tid & 63;
    const int half = lane >> 5;         // which row of the pair
    const int hl   = lane & 31;         // lane within half-wave
    const int base = blockIdx.x * CHUNK;

    const float4 wvec = *reinterpret_cast<const float4*>(w + hl * 4);
    const float  bs   = bias[0];
    const float* xp = x + (size_t)(base + wv * 64 + half) * 512 + hl * 4;

    // 32 iterations x 2 rows per wave; 512B fully-coalesced per half-wave.
#pragma unroll 8
    for (int r = 0; r < 32; ++r) {
        const float4 xv = *reinterpret_cast<const float4*>(xp + (size_t)r * 1024);
        float s = fmaf(xv.x, wvec.x, fmaf(xv.y, wvec.y, fmaf(xv.z, wvec.z, xv.w * wvec.w)));
        // 32-lane reduce: 4 DPP (VALU pipe) + 1 shuffle (xor16)
        s = dpp_add<0xB1>(s);    // quad_perm [1,0,3,2]  : xor1
        s = dpp_add<0x4E>(s);    // quad_perm [2,3,0,1]  : xor2
        s = dpp_add<0x141>(s);   // row_half_mirror      : pairs 4-groups in 8
        s = dpp_add<0x140>(s);   // row_mirror           : pairs 8-groups in 16
        s += __shfl_xor(s, 16, 64);
        if (hl == 0) u_s[wv * 64 + r * 2 + half] = s + bs;
    }
    __syncthreads();

    // Weighted inclusive scan of u_s[256]: p_i = u_i + a * p_{i-1}
    const float a = wh_p[0];
    float c = u_s[tid];
    float f = a;
#pragma unroll
    for (int s = 1; s < 64; s <<= 1) {
        float prev = __shfl_up(c, (unsigned)s, 64);
        if (lane >= s) c = fmaf(prev, f, c);
        f *= f;
    }
    // f == a^64 now; c = inclusive within wave
    if (lane == 63) wl[wv] = c;
    __syncthreads();
    if (wv > 0) {
        float seed = 0.0f;
        for (int j = 0; j < wv; ++j) seed = fmaf(seed, f, wl[j]);   // chain waves 0..wv-1
        // a^(lane+1), e in [1,64], by binary powering
        int e = lane + 1;
        float acc = 1.0f, bse = a;
#pragma unroll
        for (int b = 0; b < 7; ++b) { if (e & (1 << b)) acc *= bse; bse *= bse; }
        c = fmaf(acc * seed, 1.0f, c);
    }
    p[base + tid] = c;
    if (tid == CHUNK - 1) carry[blockIdx.x] = c;
}

// ---- K2: scan NCHUNK carries with coefficient A = a^CHUNK; write EXCLUSIVE carries. ----
__global__ __launch_bounds__(NCHUNK) void k_scan(const float* __restrict__ carry,
                                                 const float* __restrict__ wh_p,
                                                 float* __restrict__ ex_carry) {
    const int tid  = threadIdx.x;
    const int lane = tid & 63;
    const int wv   = tid >> 6;          // 8 waves
    float A = wh_p[0];
#pragma unroll
    for (int i = 0; i < 8; ++i) A *= A;         // a^256 == a^CHUNK
    float c = carry[tid];
    float f = A;
#pragma unroll
    for (int s = 1; s < 64; s <<= 1) {
        float prev = __shfl_up(c, (unsigned)s, 64);
        if (lane >= s) c = fmaf(prev, f, c);
        f *= f;
    }
    __shared__ float wl[8], wp[8];
    if (lane == 63) wl[wv] = c;
    __syncthreads();
    if (tid == 0) {
        const float A64 = f;
        float p = 0.0f;
#pragma unroll
        for (int w2 = 0; w2 < 8; ++w2) { p = fmaf(p, A64, wl[w2]); wp[w2] = p; }
    }
    __syncthreads();
    float cg = c;
    if (wv > 0) {
        int e = lane + 1;
        float bse = A, acc = 1.0f;
#pragma unroll
        for (int b = 0; b < 7; ++b) { if (e & (1 << b)) acc *= bse; bse *= bse; }
        cg = fmaf(wp[wv - 1], acc, cg);
    }
    if (tid + 1 < NCHUNK) ex_carry[tid + 1] = cg;
    if (tid == 0) ex_carry[0] = 0.0f;
}

// ---- K3: out_i = p_i + a^(ii+1) * ex_carry[chunk]; float4, 4 elems/thread. ----
__global__ __launch_bounds__(256) void k_apply(const float* __restrict__ p,
                                               const float* __restrict__ wh_p,
                                               const float* __restrict__ ex,
                                               float* __restrict__ out) {
    const int t  = blockIdx.x * 256 + threadIdx.x;  // 32768 threads
    const int i0 = t * 4;
    const int k  = i0 >> 8;
    const int ii = i0 & 255;
    const float a = wh_p[0];
    const float cseed = ex[k];
    // acc = a^(ii+1): start at a, fold bits of ii (bits 2..7 only; ii%4==0)
    float acc = a, bse = a;
#pragma unroll
    for (int b = 0; b < 8; ++b) { if (ii & (1 << b)) acc *= bse; bse *= bse; }
    const float4 pv = *reinterpret_cast<const float4*>(p + i0);
    float4 ov;
    ov.x = fmaf(acc, cseed, pv.x); acc *= a;
    ov.y = fmaf(acc, cseed, pv.y); acc *= a;
    ov.z = fmaf(acc, cseed, pv.z); acc *= a;
    ov.w = fmaf(acc, cseed, pv.w);
    *reinterpret_cast<float4*>(out + i0) = ov;
    if (i0 == B_ROWS - 4) {     // y_h duplicated tail
        out[B_ROWS]     = ov.w;
        out[B_ROWS + 1] = ov.w;
    }
}

extern "C" void kernel_launch(void* const* d_in, const int* in_sizes, int n_in,
                              void* d_out, int out_size, void* d_ws, size_t ws_size,
                              hipStream_t stream) {
    const float* x    = (const float*)d_in[0];   // (131072, 4, 128) f32
    const float* w    = (const float*)d_in[1];   // (128, 1) f32
    const float* wh   = (const float*)d_in[2];   // (1, 1) f32
    const float* bias = (const float*)d_in[3];   // (1,) f32
    float* out = (float*)d_out;                  // 131074 f32

    float* p        = (float*)d_ws;              // B_ROWS floats
    float* carry    = p + B_ROWS;                // NCHUNK floats
    float* ex_carry = carry + NCHUNK;            // NCHUNK floats

    k_dot_scan<<<NCHUNK, 256, 0, stream>>>(x, w, wh, bias, p, carry);
    k_scan<<<1, NCHUNK, 0, stream>>>(carry, wh, ex_carry);
    k_apply<<<B_ROWS / 4 / 256, 256, 0, stream>>>(p, wh, ex_carry, out);
}